// Round 8
// baseline (224.970 us; speedup 1.0000x reference)
//
#include <hip/hip_runtime.h>
#include <cmath>

#define B_   128
#define L_   256
#define HID_ 768
#define HID2_ 1536
#define CDIM_ 192
#define SDIM_ 128
#define NPROJ_ 128
#define FDIM_ 321
#define KSL_ 384            // K-slice per gemm block (HID_/2)
#define PTSTRIDE ((size_t)B_ * NPROJ_ * L_)

typedef __attribute__((ext_vector_type(8))) short bf16x8;
typedef __attribute__((ext_vector_type(4))) float f32x4;

__device__ inline unsigned short bf_hi_trunc(float x) {
    return (unsigned short)(__float_as_uint(x) >> 16);
}
__device__ inline float bf2f(unsigned short s) {
    return __uint_as_float(((unsigned int)s) << 16);
}
__device__ inline unsigned short f2bf_rne(float x) {
    unsigned int u = __float_as_uint(x);
    unsigned int r = (u + 0x7fff + ((u >> 16) & 1)) >> 16;
    return (unsigned short)r;
}

// ---------------------------------------------------------------------------
// Kernel P: proj_dirs fp32 -> bf16 hi/lo split. 128 blocks x 192 threads.
// ---------------------------------------------------------------------------
__global__ __launch_bounds__(192) void pre_kernel(
    const float* __restrict__ Pd, unsigned short* __restrict__ Pjh,
    unsigned short* __restrict__ Pjl)
{
    int i = blockIdx.x * 192 + threadIdx.x;   // float4 index, total 24576
    float4 v = ((const float4*)Pd)[i];
    ushort4 h, l;
    h.x = bf_hi_trunc(v.x); l.x = f2bf_rne(v.x - bf2f(h.x));
    h.y = bf_hi_trunc(v.y); l.y = f2bf_rne(v.y - bf2f(h.y));
    h.z = bf_hi_trunc(v.z); l.z = f2bf_rne(v.z - bf2f(h.z));
    h.w = bf_hi_trunc(v.w); l.w = f2bf_rne(v.w - bf2f(h.w));
    ((ushort4*)Pjh)[i] = h;
    ((ushort4*)Pjl)[i] = l;
}

// ---------------------------------------------------------------------------
// Stats: weighted 2-row partial (8 FMA), butterfly over the 8 same-col lanes
// (12 shfl), then 8 lanes atomicAdd to distinct addresses.  kbase is the
// TILE base column only; per-lane offset added here.  (Round-5 proven.)
// ---------------------------------------------------------------------------
__device__ inline void stats_bfly(float4 x, float4 y, float fa, float fb,
                                  int kbase, int lane, float* __restrict__ sacc)
{
    float px = x.x * fa + y.x * fb;
    float py = x.y * fa + y.y * fb;
    float pz = x.z * fa + y.z * fb;
    float pw = x.w * fa + y.w * fb;
#pragma unroll
    for (int off = 8; off < 64; off <<= 1) {
        px += __shfl_xor(px, off, 64);
        py += __shfl_xor(py, off, 64);
        pz += __shfl_xor(pz, off, 64);
        pw += __shfl_xor(pw, off, 64);
    }
    if (lane < 8) {
        float* d = &sacc[kbase + lane * 4];
        atomicAdd(d + 0, px);
        atomicAdd(d + 1, py);
        atomicAdd(d + 2, pz);
        atomicAdd(d + 3, pw);
    }
}

// ---------------------------------------------------------------------------
// Kernel C: split-bf16 MFMA GEMM + fused stats.  K-step 64, depth-1
// prefetch, single barrier/step (round-7 proven).  launch_bounds(256,4):
// VGPR settled at 72 (round 7) so the ,3 anti-spill cap is no longer
// needed; 4 blocks/CU residency (LDS 36.9KB x 4 = 147KB fits) stacks the
// round-5-proven block-overlap lever on the halved-barrier schedule.
// WRITE_SIZE ~34.3MB is the spill canary.
// ---------------------------------------------------------------------------
#define LDSROW64 136   // ushorts per 64-col row: [0:64) hi | [64:128) lo | pad
__global__ __launch_bounds__(256, 4) void gemm_mfma(
    const float* __restrict__ H, const unsigned short* __restrict__ Pjh,
    const unsigned short* __restrict__ Pjl, const int* __restrict__ tt,
    const int* __restrict__ mm, float* __restrict__ Ptp,
    float* __restrict__ part)
{
    __shared__ unsigned short Hs[2][64 * LDSROW64];   // 34816 B
    __shared__ float sacc[KSL_];                      // 1536 B
    __shared__ float sw[64];

    int tid = threadIdx.x;
    int w = tid >> 6;
    int lane = tid & 63;
    int c = lane & 15;
    int q = lane >> 4;

    int ks     = blockIdx.x & 1;
    int lchunk = (blockIdx.x >> 1) & 3;
    int b      = blockIdx.x >> 3;
    int lbase  = lchunk * 64;

    const float* Hbase = H + ((size_t)(b * L_ + lbase)) * HID_ + ks * KSL_;
    int hrow0 = tid >> 3;          // 0..31 (rows hrow0 and hrow0+32)
    int hc4   = tid & 7;           // float4 slot within 32-col half

    const unsigned short* pjh0 = Pjh + (size_t)(w * 32 + c) * HID_ + ks * KSL_ + q * 8;
    const unsigned short* pjh1 = pjh0 + (size_t)16 * HID_;
    const unsigned short* pjl0 = Pjl + (size_t)(w * 32 + c) * HID_ + ks * KSL_ + q * 8;
    const unsigned short* pjl1 = pjl0 + (size_t)16 * HID_;

    f32x4 acc[2][4] = {};
    float4 h0a, h0b, h1a, h1b;          // tile(t+1) H: 2 rows x 2 col-halves
    uint4 cah[2][2], cal[2][2];         // current A-frags [p-half][k-half]
    uint4 nah[2][2], nal[2][2];         // next    A-frags

#define LOADT(T) do {                                                         \
    int k0_ = (T) * 64;                                                       \
    h0a = *(const float4*)(Hbase + (size_t)hrow0 * HID_ + k0_ + hc4 * 4);     \
    h0b = *(const float4*)(Hbase + (size_t)hrow0 * HID_ + k0_ + 32 + hc4 * 4);\
    h1a = *(const float4*)(Hbase + (size_t)(hrow0 + 32) * HID_ + k0_ + hc4 * 4);      \
    h1b = *(const float4*)(Hbase + (size_t)(hrow0 + 32) * HID_ + k0_ + 32 + hc4 * 4); \
    nah[0][0] = *(const uint4*)(pjh0 + k0_);                                  \
    nah[0][1] = *(const uint4*)(pjh0 + k0_ + 32);                             \
    nah[1][0] = *(const uint4*)(pjh1 + k0_);                                  \
    nah[1][1] = *(const uint4*)(pjh1 + k0_ + 32);                             \
    nal[0][0] = *(const uint4*)(pjl0 + k0_);                                  \
    nal[0][1] = *(const uint4*)(pjl0 + k0_ + 32);                             \
    nal[1][0] = *(const uint4*)(pjl1 + k0_);                                  \
    nal[1][1] = *(const uint4*)(pjl1 + k0_ + 32);                             \
} while (0)

#define CVT1(V, HH, LL) do {                                                  \
    HH.x = bf_hi_trunc(V.x); LL.x = f2bf_rne(V.x - bf2f(HH.x));               \
    HH.y = bf_hi_trunc(V.y); LL.y = f2bf_rne(V.y - bf2f(HH.y));               \
    HH.z = bf_hi_trunc(V.z); LL.z = f2bf_rne(V.z - bf2f(HH.z));               \
    HH.w = bf_hi_trunc(V.w); LL.w = f2bf_rne(V.w - bf2f(HH.w));               \
} while (0)

#define CONVT(BUF, T) do {                                                    \
    ushort4 hh_, ll_;                                                         \
    CVT1(h0a, hh_, ll_);                                                      \
    *(ushort4*)&Hs[BUF][hrow0 * LDSROW64 + hc4 * 4]      = hh_;               \
    *(ushort4*)&Hs[BUF][hrow0 * LDSROW64 + 64 + hc4 * 4] = ll_;               \
    CVT1(h0b, hh_, ll_);                                                      \
    *(ushort4*)&Hs[BUF][hrow0 * LDSROW64 + 32 + hc4 * 4] = hh_;               \
    *(ushort4*)&Hs[BUF][hrow0 * LDSROW64 + 96 + hc4 * 4] = ll_;               \
    CVT1(h1a, hh_, ll_);                                                      \
    *(ushort4*)&Hs[BUF][(hrow0 + 32) * LDSROW64 + hc4 * 4]      = hh_;        \
    *(ushort4*)&Hs[BUF][(hrow0 + 32) * LDSROW64 + 64 + hc4 * 4] = ll_;        \
    CVT1(h1b, hh_, ll_);                                                      \
    *(ushort4*)&Hs[BUF][(hrow0 + 32) * LDSROW64 + 32 + hc4 * 4] = hh_;        \
    *(ushort4*)&Hs[BUF][(hrow0 + 32) * LDSROW64 + 96 + hc4 * 4] = ll_;        \
    stats_bfly(h0a, h1a, fa, fb, (T) * 64,      lane, sacc);                  \
    stats_bfly(h0b, h1b, fa, fb, (T) * 64 + 32, lane, sacc);                  \
} while (0)

#define COPYNC do {                                                           \
    cah[0][0] = nah[0][0]; cah[0][1] = nah[0][1];                             \
    cah[1][0] = nah[1][0]; cah[1][1] = nah[1][1];                             \
    cal[0][0] = nal[0][0]; cal[0][1] = nal[0][1];                             \
    cal[1][0] = nal[1][0]; cal[1][1] = nal[1][1];                             \
} while (0)

#define GEMM64(BUF) do {                                                      \
    _Pragma("unroll")                                                         \
    for (int kk = 0; kk < 2; ++kk) {                                          \
        bf16x8 bh_[4], bl_[4];                                                \
        _Pragma("unroll")                                                     \
        for (int lt = 0; lt < 4; ++lt) {                                      \
            int l_ = lt * 16 + c;                                             \
            bh_[lt] = *(const bf16x8*)&Hs[BUF][l_ * LDSROW64 + kk * 32 + q * 8];      \
            bl_[lt] = *(const bf16x8*)&Hs[BUF][l_ * LDSROW64 + 64 + kk * 32 + q * 8]; \
        }                                                                     \
        _Pragma("unroll")                                                     \
        for (int pt = 0; pt < 2; ++pt) {                                      \
            bf16x8 ah_ = *(bf16x8*)&cah[pt][kk];                              \
            bf16x8 al_ = *(bf16x8*)&cal[pt][kk];                              \
            _Pragma("unroll")                                                 \
            for (int lt = 0; lt < 4; ++lt) {                                  \
                acc[pt][lt] = __builtin_amdgcn_mfma_f32_16x16x32_bf16(ah_, bh_[lt], acc[pt][lt], 0, 0, 0); \
                acc[pt][lt] = __builtin_amdgcn_mfma_f32_16x16x32_bf16(ah_, bl_[lt], acc[pt][lt], 0, 0, 0); \
                acc[pt][lt] = __builtin_amdgcn_mfma_f32_16x16x32_bf16(al_, bh_[lt], acc[pt][lt], 0, 0, 0); \
            }                                                                 \
        }                                                                     \
    }                                                                         \
} while (0)

    // -------- prologue --------
    LOADT(0);

    int t_ = tt[b * L_ + tid];
    int m_ = mm[b * L_ + tid];
    int n0 = __syncthreads_count(t_ == 0 && m_ == 1);
    int n1 = __syncthreads_count(t_ == 1 && m_ == 1);
    float r0 = 1.f / fmaxf((float)n0, 1.f);
    float r1 = 1.f / fmaxf((float)n1, 1.f);
    if (tid < 64) {
        int tl = tt[b * L_ + lbase + tid];
        int ml = mm[b * L_ + lbase + tid];
        sw[tid] = ((tl == 0 && ml == 1) ? r0 : 0.f)
                - ((tl == 1 && ml == 1) ? r1 : 0.f);
    }
    for (int i = tid; i < KSL_; i += 256) sacc[i] = 0.f;
    __syncthreads();                 // publish sw + sacc zeros
    float fa = sw[hrow0], fb = sw[hrow0 + 32];

    COPYNC;                          // tile-0 A-frags -> current
    CONVT(0, 0);                     // tile-0 H -> Hs[0] (+stats)
    __syncthreads();                 // publish Hs[0]

    // -------- main loop: 6 K-steps of 64 --------
    for (int it = 0; it < 6; ++it) {
        int cur = it & 1;
        int nxt = cur ^ 1;

        if (it + 1 < 6) LOADT(it + 1);   // issue 12 loads; GEMM covers latency
        GEMM64(cur);                     // 48 MFMA on tile it
        if (it + 1 < 6) {
            CONVT(nxt, it + 1);          // waits H regs only (Pj still in flight)
            COPYNC;                      // drains Pj just before barrier
        }
        __syncthreads();
    }

    // -------- epilogue: Pt slice write --------
    float* Pts = Ptp + (size_t)ks * PTSTRIDE;
#pragma unroll
    for (int pt = 0; pt < 2; ++pt)
#pragma unroll
    for (int lt = 0; lt < 4; ++lt)
#pragma unroll
    for (int r = 0; r < 4; ++r) {
        int p2 = w * 32 + pt * 16 + q * 4 + r;
        int l = lbase + lt * 16 + c;
        Pts[((size_t)(b * NPROJ_ + p2)) * L_ + l] = acc[pt][lt][r];
    }

    // flush stats partials: part[b][lchunk][768], this block's k-slice half
    {
        float* pdst = part + (size_t)(b * 4 + lchunk) * HID_ + ks * KSL_;
        for (int i = tid; i < KSL_; i += 256)
            pdst[i] = sacc[i];
    }
#undef LOADT
#undef CVT1
#undef CONVT
#undef COPYNC
#undef GEMM64
}

// ---------------------------------------------------------------------------
// Kernel HO: head (blocks [0,1024)) + OT distance (blocks [1024,5120)).
// ---------------------------------------------------------------------------
__global__ __launch_bounds__(256) void headot_kernel(
    const float* __restrict__ H, const int* __restrict__ tt,
    const int* __restrict__ mm, const float* __restrict__ part,
    const float* __restrict__ Wc, const float* __restrict__ bc,
    const float* __restrict__ Ws, const float* __restrict__ bs,
    const float* __restrict__ gate, const float* __restrict__ Ptp,
    float* __restrict__ fused, float* __restrict__ dist)
{
    if (blockIdx.x < B_ * 8) {
        // ---------------- head path ----------------
        __shared__ float srep[HID2_];
        int b = blockIdx.x >> 3;
        int ochunk = (blockIdx.x & 7) * 40;
        int tid = threadIdx.x;

        const float* pp = part + (size_t)b * 4 * HID_;
        for (int h = tid; h < HID_; h += 256) {
            float a = pp[h] + pp[HID_ + h] + pp[2 * HID_ + h] + pp[3 * HID_ + h];
            srep[h]        = H[(size_t)b * L_ * HID_ + h];   // cls = H[:,0,:]
            srep[HID_ + h] = a;
        }
        __syncthreads();

        int w = tid >> 6;
        int lane = tid & 63;
        float g = 1.0f / (1.0f + expf(-gate[0]));

#pragma unroll
        for (int r = 0; r < 10; ++r) {
            int o = ochunk + r * 4 + w;
            bool isC = (o < CDIM_);
            const float4* wr = (const float4*)(isC ? (Wc + (size_t)o * HID2_)
                                                   : (Ws + (size_t)(o - CDIM_) * HID2_));
            float acc = 0.f;
#pragma unroll
            for (int u = 0; u < 6; ++u) {
                int k4 = lane + u * 64;
                float4 a = *(const float4*)&srep[k4 * 4];
                float4 ww = wr[k4];
                acc += a.x * ww.x + a.y * ww.y + a.z * ww.z + a.w * ww.w;
            }
            for (int off = 32; off; off >>= 1) acc += __shfl_xor(acc, off, 64);
            if (lane == 0) {
                float bias = isC ? bc[o] : bs[o - CDIM_];
                float scale = isC ? (1.0f - g) : g;
                fused[(size_t)b * (CDIM_ + SDIM_) + o] = (acc + bias) * scale;
            }
        }
        return;
    }

    // ---------------- OT path ----------------
    int bid = blockIdx.x - B_ * 8;
    int w = bid * 4 + (threadIdx.x >> 6);
    int lane = threadIdx.x & 63;
    int b = w >> 7;
    int p = w & (NPROJ_ - 1);

    float4 pv0 = *(const float4*)(Ptp + ((size_t)(b * NPROJ_ + p)) * L_ + lane * 4);
    float4 pv1 = *(const float4*)(Ptp + PTSTRIDE + ((size_t)(b * NPROJ_ + p)) * L_ + lane * 4);
    float4 pv = make_float4(pv0.x + pv1.x, pv0.y + pv1.y, pv0.z + pv1.z, pv0.w + pv1.w);
    int4 t4 = *(const int4*)(tt + (size_t)b * L_ + lane * 4);
    int4 m4 = *(const int4*)(mm + (size_t)b * L_ + lane * 4);

    float pvals[4] = {pv.x, pv.y, pv.z, pv.w};
    int tv[4] = {t4.x, t4.y, t4.z, t4.w};
    int mv[4] = {m4.x, m4.y, m4.z, m4.w};

    unsigned key[4];
#pragma unroll
    for (int r = 0; r < 4; ++r) {
        unsigned u = __float_as_uint(pvals[r]);
        unsigned s = (u & 0x80000000u) ? ~u : (u | 0x80000000u);
        unsigned label = (mv[r] == 1) ? (unsigned)tv[r] : 2u;
        key[r] = (s & ~3u) | label;
    }

    {   // k=2, j=1
        unsigned mn0 = min(key[0], key[1]), mx0 = max(key[0], key[1]);
        key[0] = mn0; key[1] = mx0;
        unsigned mn1 = min(key[2], key[3]), mx1 = max(key[2], key[3]);
        key[2] = mx1; key[3] = mn1;
    }
#pragma unroll
    for (int k = 4; k <= 256; k <<= 1) {
        bool up = (lane & (k >> 2)) == 0;
#pragma unroll
        for (int j = k >> 1; j >= 4; j >>= 1) {
            int lj = j >> 2;
#pragma unroll
            for (int r = 0; r < 4; ++r) {
                unsigned o = (unsigned)__shfl_xor((int)key[r], lj, 64);
                bool lower = (lane & lj) == 0;
                unsigned mn = min(key[r], o), mx = max(key[r], o);
                key[r] = (lower == up) ? mn : mx;
            }
        }
        {   // j=2
            unsigned mn0 = min(key[0], key[2]), mx0 = max(key[0], key[2]);
            key[0] = up ? mn0 : mx0; key[2] = up ? mx0 : mn0;
            unsigned mn1 = min(key[1], key[3]), mx1 = max(key[1], key[3]);
            key[1] = up ? mn1 : mx1; key[3] = up ? mx1 : mn1;
        }
        {   // j=1
            unsigned mn0 = min(key[0], key[1]), mx0 = max(key[0], key[1]);
            key[0] = up ? mn0 : mx0; key[1] = up ? mx0 : mn0;
            unsigned mn1 = min(key[2], key[3]), mx1 = max(key[2], key[3]);
            key[2] = up ? mn1 : mx1; key[3] = up ? mx1 : mn1;
        }
    }

    int lab[4];
    float tval[4];
    unsigned sincl[4];
    unsigned run = 0;
#pragma unroll
    for (int r = 0; r < 4; ++r) {
        lab[r] = (int)(key[r] & 3u);
        unsigned s = key[r] & ~3u;
        unsigned u = (s & 0x80000000u) ? (s ^ 0x80000000u) : ~s;
        tval[r] = __uint_as_float(u);
        unsigned unit = ((lab[r] == 0) ? 0x10000u : 0u) | ((lab[r] == 1) ? 1u : 0u);
        run += unit;
        sincl[r] = run;
    }
    unsigned inc = run;
#pragma unroll
    for (int d = 1; d < 64; d <<= 1) {
        unsigned tt2 = (unsigned)__shfl_up((int)inc, d, 64);
        if (lane >= d) inc += tt2;
    }
    unsigned ex = inc - run;
    unsigned total = (unsigned)__shfl((int)inc, 63, 64);
    int n0 = (int)(total >> 16), n1 = (int)(total & 0xffffu);
    int m = (n0 < n1) ? n0 : n1;

    float ssum = 0.f;
#pragma unroll
    for (int r = 0; r < 4; ++r) {
        unsigned C = ex + sincl[r];
        int c0 = (int)(C >> 16), c1 = (int)(C & 0xffffu);
        int s0 = (lab[r] == 0), s1 = (lab[r] == 1);
        int wi = abs(min(c0, m) - min(c1, m));
        int wp = abs(min(c0 - s0, m) - min(c1 - s1, m));
        ssum += tval[r] * (float)(wp - wi);
    }
    for (int off = 32; off; off >>= 1) ssum += __shfl_xor(ssum, off, 64);
    if (lane == 0) dist[b * NPROJ_ + p] = ssum / (float)((m > 1) ? m : 1);
}

// ---------------------------------------------------------------------------
// Kernel E: max over p, layernorm, classifier (unchanged)
// ---------------------------------------------------------------------------
__global__ __launch_bounds__(64) void final_kernel(
    const float* __restrict__ fused, const float* __restrict__ dist,
    const float* __restrict__ ln_g, const float* __restrict__ ln_b,
    const float* __restrict__ Wcls, const float* __restrict__ bcls,
    float* __restrict__ out)
{
    int b = blockIdx.x;
    int lane = threadIdx.x;

    float mx = fmaxf(dist[b * NPROJ_ + lane], dist[b * NPROJ_ + 64 + lane]);
    for (int off = 32; off; off >>= 1) mx = fmaxf(mx, __shfl_xor(mx, off, 64));

    float fv[6];
    float sum = 0.f, sq = 0.f;
#pragma unroll
    for (int u = 0; u < 6; ++u) {
        int j = lane + u * 64;
        float x = 0.f;
        if (j < CDIM_ + SDIM_) x = fused[(size_t)b * (CDIM_ + SDIM_) + j];
        else if (j == CDIM_ + SDIM_) x = mx;
        fv[u] = x;
        if (j < FDIM_) { sum += x; sq += x * x; }
    }
    for (int off = 32; off; off >>= 1) {
        sum += __shfl_xor(sum, off, 64);
        sq  += __shfl_xor(sq,  off, 64);
    }
    float mu = sum / (float)FDIM_;
    float var = sq / (float)FDIM_ - mu * mu;
    float inv = rsqrtf(var + 1e-5f);

    float d0 = 0.f, d1 = 0.f;
#pragma unroll
    for (int u = 0; u < 6; ++u) {
        int j = lane + u * 64;
        if (j < FDIM_) {
            float nx = (fv[u] - mu) * inv * ln_g[j] + ln_b[j];
            d0 += nx * Wcls[j];
            d1 += nx * Wcls[FDIM_ + j];
        }
    }
    for (int off = 32; off; off >>= 1) {
        d0 += __shfl_xor(d0, off, 64);
        d1 += __shfl_xor(d1, off, 64);
    }
    if (lane == 0) {
        out[b * 2 + 0] = d0 + bcls[0];
        out[b * 2 + 1] = d1 + bcls[1];
    }
}

// ---------------------------------------------------------------------------
extern "C" void kernel_launch(void* const* d_in, const int* in_sizes, int n_in,
                              void* d_out, int out_size, void* d_ws, size_t ws_size,
                              hipStream_t stream)
{
    const float* H    = (const float*)d_in[0];
    const int*   tt   = (const int*)d_in[1];
    const int*   mm   = (const int*)d_in[2];
    const float* Wc   = (const float*)d_in[3];
    const float* bc   = (const float*)d_in[4];
    const float* Ws   = (const float*)d_in[5];
    const float* bs   = (const float*)d_in[6];
    const float* gate = (const float*)d_in[7];
    const float* ln_g = (const float*)d_in[8];
    const float* ln_b = (const float*)d_in[9];
    const float* Wcls = (const float*)d_in[10];
    const float* bcls = (const float*)d_in[11];
    const float* Pd   = (const float*)d_in[12];
    float* out = (float*)d_out;

    float* ws = (float*)d_ws;
    float* Ptp   = ws;                                       // 2 x 4194304 fl
    float* part  = Ptp + 2 * PTSTRIDE;                       // 128*4*768 fl
    float* fused = part + (size_t)B_ * 4 * HID_;             // 128*320 fl
    float* dist  = fused + (size_t)B_ * (CDIM_ + SDIM_);     // 128*128 fl
    unsigned short* Pjh = (unsigned short*)(dist + (size_t)B_ * NPROJ_);
    unsigned short* Pjl = Pjh + (size_t)NPROJ_ * HID_;

    pre_kernel<<<128, 192, 0, stream>>>(Pd, Pjh, Pjl);
    gemm_mfma<<<B_ * 8, 256, 0, stream>>>(H, Pjh, Pjl, tt, mm, Ptp, part);
    headot_kernel<<<B_ * 8 + B_ * NPROJ_ / 4, 256, 0, stream>>>(
        H, tt, mm, part, Wc, bc, Ws, bs, gate, Ptp, fused, dist);
    final_kernel<<<B_, 64, 0, stream>>>(fused, dist, ln_g, ln_b, Wcls, bcls, out);
}

// Round 9
// 215.387 us; speedup vs baseline: 1.0445x; 1.0445x over previous
//
#include <hip/hip_runtime.h>
#include <cmath>

#define B_   128
#define L_   256
#define HID_ 768
#define HID2_ 1536
#define CDIM_ 192
#define SDIM_ 128
#define NPROJ_ 128
#define FDIM_ 321
#define KSL_ 384            // K-slice per gemm block (HID_/2)
#define PTSTRIDE ((size_t)B_ * NPROJ_ * L_)

typedef __attribute__((ext_vector_type(8))) short bf16x8;
typedef __attribute__((ext_vector_type(4))) float f32x4;

__device__ inline unsigned short f2bf_rne(float x) {
    unsigned int u = __float_as_uint(x);
    unsigned int r = (u + 0x7fff + ((u >> 16) & 1)) >> 16;
    return (unsigned short)r;
}

// ---------------------------------------------------------------------------
// Kernel P: proj_dirs fp32 -> bf16 (RNE, single precision level).
// 128 blocks x 192 threads.  (lo-correction dropped this round: Pt errors
// ~2e-3 vs 3.4e-2 threshold, and Pt only feeds the OT distance.)
// ---------------------------------------------------------------------------
__global__ __launch_bounds__(192) void pre_kernel(
    const float* __restrict__ Pd, unsigned short* __restrict__ Pjh)
{
    int i = blockIdx.x * 192 + threadIdx.x;   // float4 index, total 24576
    float4 v = ((const float4*)Pd)[i];
    ushort4 h;
    h.x = f2bf_rne(v.x);
    h.y = f2bf_rne(v.y);
    h.z = f2bf_rne(v.z);
    h.w = f2bf_rne(v.w);
    ((ushort4*)Pjh)[i] = h;
}

// ---------------------------------------------------------------------------
// Stats: weighted 2-row partial (8 FMA), butterfly over the 8 same-col lanes
// (12 shfl), then 8 lanes atomicAdd to distinct addresses.  kbase is the
// TILE base column only; per-lane offset added here.  (Round-5/7 proven.)
// ---------------------------------------------------------------------------
__device__ inline void stats_bfly(float4 x, float4 y, float fa, float fb,
                                  int kbase, int lane, float* __restrict__ sacc)
{
    float px = x.x * fa + y.x * fb;
    float py = x.y * fa + y.y * fb;
    float pz = x.z * fa + y.z * fb;
    float pw = x.w * fa + y.w * fb;
#pragma unroll
    for (int off = 8; off < 64; off <<= 1) {
        px += __shfl_xor(px, off, 64);
        py += __shfl_xor(py, off, 64);
        pz += __shfl_xor(pz, off, 64);
        pw += __shfl_xor(pw, off, 64);
    }
    if (lane < 8) {
        float* d = &sacc[kbase + lane * 4];
        atomicAdd(d + 0, px);
        atomicAdd(d + 1, py);
        atomicAdd(d + 2, pz);
        atomicAdd(d + 3, pw);
    }
}

// ---------------------------------------------------------------------------
// Kernel C: bf16 MFMA GEMM + fused stats.  Round-7 schedule (K-step 64,
// depth-1 prefetch, single barrier/step) with the split-precision machinery
// removed: 1 MFMA product instead of 3, Pj frags/LDS halved, convert is a
// single RNE per element.  VGPR ~100 -> (256,4) fits without spill
// (WRITE_SIZE ~34.3MB is the spill canary; round-8's cap-induced spill
// came from the 2x-larger fragment state).
// ---------------------------------------------------------------------------
#define LDSROW64 72   // ushorts per 64-col row: 64 bf16 + 8 pad
__global__ __launch_bounds__(256, 4) void gemm_mfma(
    const float* __restrict__ H, const unsigned short* __restrict__ Pjh,
    const int* __restrict__ tt, const int* __restrict__ mm,
    float* __restrict__ Ptp, float* __restrict__ part)
{
    __shared__ unsigned short Hs[2][64 * LDSROW64];   // 18432 B
    __shared__ float sacc[KSL_];                      // 1536 B
    __shared__ float sw[64];

    int tid = threadIdx.x;
    int w = tid >> 6;
    int lane = tid & 63;
    int c = lane & 15;
    int q = lane >> 4;

    int ks     = blockIdx.x & 1;
    int lchunk = (blockIdx.x >> 1) & 3;
    int b      = blockIdx.x >> 3;
    int lbase  = lchunk * 64;

    const float* Hbase = H + ((size_t)(b * L_ + lbase)) * HID_ + ks * KSL_;
    int hrow0 = tid >> 3;          // 0..31 (rows hrow0 and hrow0+32)
    int hc4   = tid & 7;           // float4 slot within 32-col half

    const unsigned short* pjh0 = Pjh + (size_t)(w * 32 + c) * HID_ + ks * KSL_ + q * 8;
    const unsigned short* pjh1 = pjh0 + (size_t)16 * HID_;

    f32x4 acc[2][4] = {};
    float4 h0a, h0b, h1a, h1b;          // tile(t+1) H: 2 rows x 2 col-halves
    uint4 cah[2][2];                    // current A-frags [p-half][k-half]
    uint4 nah[2][2];                    // next    A-frags

#define LOADT(T) do {                                                         \
    int k0_ = (T) * 64;                                                       \
    h0a = *(const float4*)(Hbase + (size_t)hrow0 * HID_ + k0_ + hc4 * 4);     \
    h0b = *(const float4*)(Hbase + (size_t)hrow0 * HID_ + k0_ + 32 + hc4 * 4);\
    h1a = *(const float4*)(Hbase + (size_t)(hrow0 + 32) * HID_ + k0_ + hc4 * 4);      \
    h1b = *(const float4*)(Hbase + (size_t)(hrow0 + 32) * HID_ + k0_ + 32 + hc4 * 4); \
    nah[0][0] = *(const uint4*)(pjh0 + k0_);                                  \
    nah[0][1] = *(const uint4*)(pjh0 + k0_ + 32);                             \
    nah[1][0] = *(const uint4*)(pjh1 + k0_);                                  \
    nah[1][1] = *(const uint4*)(pjh1 + k0_ + 32);                             \
} while (0)

#define CVT1(V, HH) do {                                                      \
    HH.x = f2bf_rne(V.x);                                                     \
    HH.y = f2bf_rne(V.y);                                                     \
    HH.z = f2bf_rne(V.z);                                                     \
    HH.w = f2bf_rne(V.w);                                                     \
} while (0)

#define CONVT(BUF, T) do {                                                    \
    ushort4 hh_;                                                              \
    CVT1(h0a, hh_);                                                           \
    *(ushort4*)&Hs[BUF][hrow0 * LDSROW64 + hc4 * 4]      = hh_;               \
    CVT1(h0b, hh_);                                                           \
    *(ushort4*)&Hs[BUF][hrow0 * LDSROW64 + 32 + hc4 * 4] = hh_;               \
    CVT1(h1a, hh_);                                                           \
    *(ushort4*)&Hs[BUF][(hrow0 + 32) * LDSROW64 + hc4 * 4]      = hh_;        \
    CVT1(h1b, hh_);                                                           \
    *(ushort4*)&Hs[BUF][(hrow0 + 32) * LDSROW64 + 32 + hc4 * 4] = hh_;        \
    stats_bfly(h0a, h1a, fa, fb, (T) * 64,      lane, sacc);                  \
    stats_bfly(h0b, h1b, fa, fb, (T) * 64 + 32, lane, sacc);                  \
} while (0)

#define COPYNC do {                                                           \
    cah[0][0] = nah[0][0]; cah[0][1] = nah[0][1];                             \
    cah[1][0] = nah[1][0]; cah[1][1] = nah[1][1];                             \
} while (0)

#define GEMM64(BUF) do {                                                      \
    _Pragma("unroll")                                                         \
    for (int kk = 0; kk < 2; ++kk) {                                          \
        bf16x8 bh_[4];                                                        \
        _Pragma("unroll")                                                     \
        for (int lt = 0; lt < 4; ++lt) {                                      \
            int l_ = lt * 16 + c;                                             \
            bh_[lt] = *(const bf16x8*)&Hs[BUF][l_ * LDSROW64 + kk * 32 + q * 8]; \
        }                                                                     \
        _Pragma("unroll")                                                     \
        for (int pt = 0; pt < 2; ++pt) {                                      \
            bf16x8 ah_ = *(bf16x8*)&cah[pt][kk];                              \
            _Pragma("unroll")                                                 \
            for (int lt = 0; lt < 4; ++lt) {                                  \
                acc[pt][lt] = __builtin_amdgcn_mfma_f32_16x16x32_bf16(ah_, bh_[lt], acc[pt][lt], 0, 0, 0); \
            }                                                                 \
        }                                                                     \
    }                                                                         \
} while (0)

    // -------- prologue --------
    LOADT(0);

    int t_ = tt[b * L_ + tid];
    int m_ = mm[b * L_ + tid];
    int n0 = __syncthreads_count(t_ == 0 && m_ == 1);
    int n1 = __syncthreads_count(t_ == 1 && m_ == 1);
    float r0 = 1.f / fmaxf((float)n0, 1.f);
    float r1 = 1.f / fmaxf((float)n1, 1.f);
    if (tid < 64) {
        int tl = tt[b * L_ + lbase + tid];
        int ml = mm[b * L_ + lbase + tid];
        sw[tid] = ((tl == 0 && ml == 1) ? r0 : 0.f)
                - ((tl == 1 && ml == 1) ? r1 : 0.f);
    }
    for (int i = tid; i < KSL_; i += 256) sacc[i] = 0.f;
    __syncthreads();                 // publish sw + sacc zeros
    float fa = sw[hrow0], fb = sw[hrow0 + 32];

    COPYNC;                          // tile-0 A-frags -> current
    CONVT(0, 0);                     // tile-0 H -> Hs[0] (+stats)
    __syncthreads();                 // publish Hs[0]

    // -------- main loop: 6 K-steps of 64 --------
    for (int it = 0; it < 6; ++it) {
        int cur = it & 1;
        int nxt = cur ^ 1;

        if (it + 1 < 6) LOADT(it + 1);   // issue 8 loads; GEMM covers latency
        GEMM64(cur);                     // 16 MFMA on tile it
        if (it + 1 < 6) {
            CONVT(nxt, it + 1);          // waits H regs only (Pj still in flight)
            COPYNC;                      // drains Pj just before barrier
        }
        __syncthreads();
    }

    // -------- epilogue: Pt slice write --------
    float* Pts = Ptp + (size_t)ks * PTSTRIDE;
#pragma unroll
    for (int pt = 0; pt < 2; ++pt)
#pragma unroll
    for (int lt = 0; lt < 4; ++lt)
#pragma unroll
    for (int r = 0; r < 4; ++r) {
        int p2 = w * 32 + pt * 16 + q * 4 + r;
        int l = lbase + lt * 16 + c;
        Pts[((size_t)(b * NPROJ_ + p2)) * L_ + l] = acc[pt][lt][r];
    }

    // flush stats partials: part[b][lchunk][768], this block's k-slice half
    {
        float* pdst = part + (size_t)(b * 4 + lchunk) * HID_ + ks * KSL_;
        for (int i = tid; i < KSL_; i += 256)
            pdst[i] = sacc[i];
    }
#undef LOADT
#undef CVT1
#undef CONVT
#undef COPYNC
#undef GEMM64
}

// ---------------------------------------------------------------------------
// Kernel HO: head (blocks [0,1024)) + OT distance (blocks [1024,5120)).
// ---------------------------------------------------------------------------
__global__ __launch_bounds__(256) void headot_kernel(
    const float* __restrict__ H, const int* __restrict__ tt,
    const int* __restrict__ mm, const float* __restrict__ part,
    const float* __restrict__ Wc, const float* __restrict__ bc,
    const float* __restrict__ Ws, const float* __restrict__ bs,
    const float* __restrict__ gate, const float* __restrict__ Ptp,
    float* __restrict__ fused, float* __restrict__ dist)
{
    if (blockIdx.x < B_ * 8) {
        // ---------------- head path ----------------
        __shared__ float srep[HID2_];
        int b = blockIdx.x >> 3;
        int ochunk = (blockIdx.x & 7) * 40;
        int tid = threadIdx.x;

        const float* pp = part + (size_t)b * 4 * HID_;
        for (int h = tid; h < HID_; h += 256) {
            float a = pp[h] + pp[HID_ + h] + pp[2 * HID_ + h] + pp[3 * HID_ + h];
            srep[h]        = H[(size_t)b * L_ * HID_ + h];   // cls = H[:,0,:]
            srep[HID_ + h] = a;
        }
        __syncthreads();

        int w = tid >> 6;
        int lane = tid & 63;
        float g = 1.0f / (1.0f + expf(-gate[0]));

#pragma unroll
        for (int r = 0; r < 10; ++r) {
            int o = ochunk + r * 4 + w;
            bool isC = (o < CDIM_);
            const float4* wr = (const float4*)(isC ? (Wc + (size_t)o * HID2_)
                                                   : (Ws + (size_t)(o - CDIM_) * HID2_));
            float acc = 0.f;
#pragma unroll
            for (int u = 0; u < 6; ++u) {
                int k4 = lane + u * 64;
                float4 a = *(const float4*)&srep[k4 * 4];
                float4 ww = wr[k4];
                acc += a.x * ww.x + a.y * ww.y + a.z * ww.z + a.w * ww.w;
            }
            for (int off = 32; off; off >>= 1) acc += __shfl_xor(acc, off, 64);
            if (lane == 0) {
                float bias = isC ? bc[o] : bs[o - CDIM_];
                float scale = isC ? (1.0f - g) : g;
                fused[(size_t)b * (CDIM_ + SDIM_) + o] = (acc + bias) * scale;
            }
        }
        return;
    }

    // ---------------- OT path ----------------
    int bid = blockIdx.x - B_ * 8;
    int w = bid * 4 + (threadIdx.x >> 6);
    int lane = threadIdx.x & 63;
    int b = w >> 7;
    int p = w & (NPROJ_ - 1);

    float4 pv0 = *(const float4*)(Ptp + ((size_t)(b * NPROJ_ + p)) * L_ + lane * 4);
    float4 pv1 = *(const float4*)(Ptp + PTSTRIDE + ((size_t)(b * NPROJ_ + p)) * L_ + lane * 4);
    float4 pv = make_float4(pv0.x + pv1.x, pv0.y + pv1.y, pv0.z + pv1.z, pv0.w + pv1.w);
    int4 t4 = *(const int4*)(tt + (size_t)b * L_ + lane * 4);
    int4 m4 = *(const int4*)(mm + (size_t)b * L_ + lane * 4);

    float pvals[4] = {pv.x, pv.y, pv.z, pv.w};
    int tv[4] = {t4.x, t4.y, t4.z, t4.w};
    int mv[4] = {m4.x, m4.y, m4.z, m4.w};

    unsigned key[4];
#pragma unroll
    for (int r = 0; r < 4; ++r) {
        unsigned u = __float_as_uint(pvals[r]);
        unsigned s = (u & 0x80000000u) ? ~u : (u | 0x80000000u);
        unsigned label = (mv[r] == 1) ? (unsigned)tv[r] : 2u;
        key[r] = (s & ~3u) | label;
    }

    {   // k=2, j=1
        unsigned mn0 = min(key[0], key[1]), mx0 = max(key[0], key[1]);
        key[0] = mn0; key[1] = mx0;
        unsigned mn1 = min(key[2], key[3]), mx1 = max(key[2], key[3]);
        key[2] = mx1; key[3] = mn1;
    }
#pragma unroll
    for (int k = 4; k <= 256; k <<= 1) {
        bool up = (lane & (k >> 2)) == 0;
#pragma unroll
        for (int j = k >> 1; j >= 4; j >>= 1) {
            int lj = j >> 2;
#pragma unroll
            for (int r = 0; r < 4; ++r) {
                unsigned o = (unsigned)__shfl_xor((int)key[r], lj, 64);
                bool lower = (lane & lj) == 0;
                unsigned mn = min(key[r], o), mx = max(key[r], o);
                key[r] = (lower == up) ? mn : mx;
            }
        }
        {   // j=2
            unsigned mn0 = min(key[0], key[2]), mx0 = max(key[0], key[2]);
            key[0] = up ? mn0 : mx0; key[2] = up ? mx0 : mn0;
            unsigned mn1 = min(key[1], key[3]), mx1 = max(key[1], key[3]);
            key[1] = up ? mn1 : mx1; key[3] = up ? mx1 : mn1;
        }
        {   // j=1
            unsigned mn0 = min(key[0], key[1]), mx0 = max(key[0], key[1]);
            key[0] = up ? mn0 : mx0; key[1] = up ? mx0 : mn0;
            unsigned mn1 = min(key[2], key[3]), mx1 = max(key[2], key[3]);
            key[2] = up ? mn1 : mx1; key[3] = up ? mx1 : mn1;
        }
    }

    int lab[4];
    float tval[4];
    unsigned sincl[4];
    unsigned run = 0;
#pragma unroll
    for (int r = 0; r < 4; ++r) {
        lab[r] = (int)(key[r] & 3u);
        unsigned s = key[r] & ~3u;
        unsigned u = (s & 0x80000000u) ? (s ^ 0x80000000u) : ~s;
        tval[r] = __uint_as_float(u);
        unsigned unit = ((lab[r] == 0) ? 0x10000u : 0u) | ((lab[r] == 1) ? 1u : 0u);
        run += unit;
        sincl[r] = run;
    }
    unsigned inc = run;
#pragma unroll
    for (int d = 1; d < 64; d <<= 1) {
        unsigned tt2 = (unsigned)__shfl_up((int)inc, d, 64);
        if (lane >= d) inc += tt2;
    }
    unsigned ex = inc - run;
    unsigned total = (unsigned)__shfl((int)inc, 63, 64);
    int n0 = (int)(total >> 16), n1 = (int)(total & 0xffffu);
    int m = (n0 < n1) ? n0 : n1;

    float ssum = 0.f;
#pragma unroll
    for (int r = 0; r < 4; ++r) {
        unsigned C = ex + sincl[r];
        int c0 = (int)(C >> 16), c1 = (int)(C & 0xffffu);
        int s0 = (lab[r] == 0), s1 = (lab[r] == 1);
        int wi = abs(min(c0, m) - min(c1, m));
        int wp = abs(min(c0 - s0, m) - min(c1 - s1, m));
        ssum += tval[r] * (float)(wp - wi);
    }
    for (int off = 32; off; off >>= 1) ssum += __shfl_xor(ssum, off, 64);
    if (lane == 0) dist[b * NPROJ_ + p] = ssum / (float)((m > 1) ? m : 1);
}

// ---------------------------------------------------------------------------
// Kernel E: max over p, layernorm, classifier (unchanged)
// ---------------------------------------------------------------------------
__global__ __launch_bounds__(64) void final_kernel(
    const float* __restrict__ fused, const float* __restrict__ dist,
    const float* __restrict__ ln_g, const float* __restrict__ ln_b,
    const float* __restrict__ Wcls, const float* __restrict__ bcls,
    float* __restrict__ out)
{
    int b = blockIdx.x;
    int lane = threadIdx.x;

    float mx = fmaxf(dist[b * NPROJ_ + lane], dist[b * NPROJ_ + 64 + lane]);
    for (int off = 32; off; off >>= 1) mx = fmaxf(mx, __shfl_xor(mx, off, 64));

    float fv[6];
    float sum = 0.f, sq = 0.f;
#pragma unroll
    for (int u = 0; u < 6; ++u) {
        int j = lane + u * 64;
        float x = 0.f;
        if (j < CDIM_ + SDIM_) x = fused[(size_t)b * (CDIM_ + SDIM_) + j];
        else if (j == CDIM_ + SDIM_) x = mx;
        fv[u] = x;
        if (j < FDIM_) { sum += x; sq += x * x; }
    }
    for (int off = 32; off; off >>= 1) {
        sum += __shfl_xor(sum, off, 64);
        sq  += __shfl_xor(sq,  off, 64);
    }
    float mu = sum / (float)FDIM_;
    float var = sq / (float)FDIM_ - mu * mu;
    float inv = rsqrtf(var + 1e-5f);

    float d0 = 0.f, d1 = 0.f;
#pragma unroll
    for (int u = 0; u < 6; ++u) {
        int j = lane + u * 64;
        if (j < FDIM_) {
            float nx = (fv[u] - mu) * inv * ln_g[j] + ln_b[j];
            d0 += nx * Wcls[j];
            d1 += nx * Wcls[FDIM_ + j];
        }
    }
    for (int off = 32; off; off >>= 1) {
        d0 += __shfl_xor(d0, off, 64);
        d1 += __shfl_xor(d1, off, 64);
    }
    if (lane == 0) {
        out[b * 2 + 0] = d0 + bcls[0];
        out[b * 2 + 1] = d1 + bcls[1];
    }
}

// ---------------------------------------------------------------------------
extern "C" void kernel_launch(void* const* d_in, const int* in_sizes, int n_in,
                              void* d_out, int out_size, void* d_ws, size_t ws_size,
                              hipStream_t stream)
{
    const float* H    = (const float*)d_in[0];
    const int*   tt   = (const int*)d_in[1];
    const int*   mm   = (const int*)d_in[2];
    const float* Wc   = (const float*)d_in[3];
    const float* bc   = (const float*)d_in[4];
    const float* Ws   = (const float*)d_in[5];
    const float* bs   = (const float*)d_in[6];
    const float* gate = (const float*)d_in[7];
    const float* ln_g = (const float*)d_in[8];
    const float* ln_b = (const float*)d_in[9];
    const float* Wcls = (const float*)d_in[10];
    const float* bcls = (const float*)d_in[11];
    const float* Pd   = (const float*)d_in[12];
    float* out = (float*)d_out;

    float* ws = (float*)d_ws;
    float* Ptp   = ws;                                       // 2 x 4194304 fl
    float* part  = Ptp + 2 * PTSTRIDE;                       // 128*4*768 fl
    float* fused = part + (size_t)B_ * 4 * HID_;             // 128*320 fl
    float* dist  = fused + (size_t)B_ * (CDIM_ + SDIM_);     // 128*128 fl
    unsigned short* Pjh = (unsigned short*)(dist + (size_t)B_ * NPROJ_);

    pre_kernel<<<128, 192, 0, stream>>>(Pd, Pjh);
    gemm_mfma<<<B_ * 8, 256, 0, stream>>>(H, Pjh, tt, mm, Ptp, part);
    headot_kernel<<<B_ * 8 + B_ * NPROJ_ / 4, 256, 0, stream>>>(
        H, tt, mm, part, Wc, bc, Ws, bs, gate, Ptp, fused, dist);
    final_kernel<<<B_, 64, 0, stream>>>(fused, dist, ln_g, ln_b, Wcls, bcls, out);
}